// Round 6
// baseline (172.888 us; speedup 1.0000x reference)
//
#include <hip/hip_runtime.h>
#include <hip/hip_bf16.h>

// GaussianAttention: S=512, B=32, T=1024, E=512, Q=128. f32 in / f32 out.
// out = [ new_context (S*B*E) | mean (S*B) ].
//
// KA (fused dot+scan): one block per b (32 x 512 thr).
//   Phase 1: wave w handles 64 s-values serially; per s: 64 lanes x float2
//            coalesced read of query[s][b][:], shuffle-reduce -> mraw/std LDS.
//   Phase 2: wave 0 does serial-8 + shuffle inclusive scan -> mean; writes
//            out_mean global.
//   Phase 3: block writes mean/std [B,S] contiguous to ws for KB.
// KB: block = (16-s chunk, b): union truncated Gaussian window; each emb row
//     read once, 16 weights from LDS, 16 float4 accumulators.
//     Weights < exp(-20) dropped (tail < 1e-5 vs measured floor 0.03).

#define S_DIM 512
#define B_DIM 32
#define T_DIM 1024
#define E_DIM 512
#define Q_DIM 128
#define WIN_CUT 20.0f
#define CH 16     // s-values per KB block
#define TSEG 64   // t-segment for weight staging

// KA: one block per b, 512 threads (8 waves).
__global__ __launch_bounds__(512) void dot_scan_kernel(
    const float* __restrict__ query,     // [S,B,Q]
    const float* __restrict__ position,  // [S,B]
    const float* __restrict__ W,         // [2,Q]
    const float* __restrict__ bias,      // [2]
    float* __restrict__ ws_mean,         // [B,S]
    float* __restrict__ ws_std,          // [B,S]
    float* __restrict__ out_mean)        // [S,B] f32
{
    __shared__ float l_mraw[S_DIM];
    __shared__ float l_std[S_DIM];
    __shared__ float l_mean[S_DIM];
    const int b    = blockIdx.x;
    const int tid  = threadIdx.x;
    const int wave = tid >> 6;
    const int lane = tid & 63;

    const float w0a = W[2 * lane],         w0b = W[2 * lane + 1];
    const float w1a = W[Q_DIM + 2 * lane], w1b = W[Q_DIM + 2 * lane + 1];
    const float b0 = bias[0], b1 = bias[1];

    // Phase 1: 8 waves x 64 s each.
    for (int i = 0; i < 64; ++i) {
        const int s = wave * 64 + i;
        const float2 v = ((const float2*)(query + ((size_t)s * B_DIM + b) * Q_DIM))[lane];
        float d0 = v.x * w0a + v.y * w0b;
        float d1 = v.x * w1a + v.y * w1b;
        #pragma unroll
        for (int off = 32; off; off >>= 1) {
            d0 += __shfl_down(d0, off);
            d1 += __shfl_down(d1, off);
        }
        if (lane == 0) {
            l_mraw[s] = __expf(d0 + b0);
            l_std[s]  = __expf(d1 + b1);
        }
    }
    __syncthreads();

    // Phase 2: wave 0 scans 512 values (serial-8 per lane + shuffle scan).
    if (wave == 0) {
        float v[8], pre[8], run = 0.f;
        #pragma unroll
        for (int j = 0; j < 8; ++j) { v[j] = l_mraw[lane * 8 + j]; run += v[j]; pre[j] = run; }
        float tot = run, sc = tot;
        #pragma unroll
        for (int off = 1; off < 64; off <<= 1) {
            float u = __shfl_up(sc, off);
            if (lane >= off) sc += u;
        }
        float excl = sc - tot;
        #pragma unroll
        for (int j = 0; j < 8; ++j) {
            const int s = lane * 8 + j;
            float m = position[(size_t)s * B_DIM + b] + (excl + pre[j]) * 0.05f;
            l_mean[s] = m;
            out_mean[(size_t)s * B_DIM + b] = m;
        }
    }
    __syncthreads();

    // Phase 3: contiguous [B,S] stores for KB.
    ws_mean[(size_t)b * S_DIM + tid] = l_mean[tid];
    ws_std[(size_t)b * S_DIM + tid]  = l_std[tid];
}

// KB: grid (S/CH, B), 128 threads. 16 s share each emb-row read.
__global__ __launch_bounds__(128) void ctx_kernel(
    const float* __restrict__ emb,     // [T,B,E]
    const float* __restrict__ mask,    // [T,B]
    const float* __restrict__ ws_mean, // [B,S]
    const float* __restrict__ ws_std,  // [B,S]
    float* __restrict__ out)           // [S,B,E]
{
    __shared__ float lds_w[TSEG * CH];
    __shared__ float lds_mean[CH], lds_std[CH];
    __shared__ int s_tlo, s_thi;
    const int c = blockIdx.x, b = blockIdx.y;
    const int s0 = c * CH;
    const int tid = threadIdx.x;

    if (tid < CH) {
        lds_mean[tid] = ws_mean[(size_t)b * S_DIM + s0 + tid];
        lds_std[tid]  = ws_std[(size_t)b * S_DIM + s0 + tid];
    }
    __syncthreads();
    if (tid == 0) {
        float lo = 1e30f, hi = -1e30f;
        #pragma unroll
        for (int i = 0; i < CH; ++i) {
            float r = __fsqrt_rn(WIN_CUT / lds_std[i]);
            lo = fminf(lo, lds_mean[i] - r);
            hi = fmaxf(hi, lds_mean[i] + r);
        }
        int tlo = (int)floorf(lo);
        if (tlo < 0) tlo = 0; if (tlo > T_DIM - 1) tlo = T_DIM - 1;
        int thi = (int)ceilf(hi);
        if (thi > T_DIM - 1) thi = T_DIM - 1; if (thi < tlo) thi = tlo;
        s_tlo = tlo; s_thi = thi;
    }
    __syncthreads();
    const int tlo = s_tlo, thi = s_thi;

    float4 acc[CH];
    #pragma unroll
    for (int i = 0; i < CH; ++i) acc[i] = float4{0.f, 0.f, 0.f, 0.f};

    for (int tseg = tlo; tseg <= thi; tseg += TSEG) {
        {
            const int toff = tid >> 1;
            const int ibase = (tid & 1) * 8;
            const int t = tseg + toff;
            float mv = 0.f;
            if (t <= thi) mv = mask[(size_t)t * B_DIM + b];
            #pragma unroll
            for (int j = 0; j < 8; ++j) {
                int i = ibase + j;
                float d = lds_mean[i] - (float)t;
                float w = (t <= thi) ? __expf(-lds_std[i] * d * d) * mv : 0.f;
                lds_w[toff * CH + i] = w;
            }
        }
        __syncthreads();
        const int tend = (thi < tseg + TSEG - 1) ? thi : (tseg + TSEG - 1);
        for (int t = tseg; t <= tend; ++t) {
            const int toff = t - tseg;
            const float4 v =
                ((const float4*)(emb + ((size_t)t * B_DIM + b) * E_DIM))[tid];
            const float* wrow = lds_w + toff * CH;
            #pragma unroll
            for (int i = 0; i < CH; ++i) {
                float w = wrow[i];
                acc[i].x += w * v.x; acc[i].y += w * v.y;
                acc[i].z += w * v.z; acc[i].w += w * v.w;
            }
        }
        __syncthreads();
    }
    #pragma unroll
    for (int i = 0; i < CH; ++i)
        ((float4*)(out + ((size_t)(s0 + i) * B_DIM + b) * E_DIM))[tid] = acc[i];
}

extern "C" void kernel_launch(void* const* d_in, const int* in_sizes, int n_in,
                              void* d_out, int out_size, void* d_ws, size_t ws_size,
                              hipStream_t stream) {
    const float* query = (const float*)d_in[0]; // [S,B,Q]
    const float* emb   = (const float*)d_in[1]; // [T,B,E]
    const float* mask  = (const float*)d_in[2]; // [T,B]
    const float* pos   = (const float*)d_in[3]; // [S,B]
    const float* W     = (const float*)d_in[4]; // [2,Q]
    const float* bias  = (const float*)d_in[5]; // [2]

    float* out_ctx  = (float*)d_out;                            // S*B*E
    float* out_mean = out_ctx + (size_t)S_DIM * B_DIM * E_DIM;  // S*B

    float* ws_mean = (float*)d_ws;                      // [B,S]
    float* ws_std  = ws_mean + (size_t)S_DIM * B_DIM;   // [B,S] (128 KiB)

    dot_scan_kernel<<<B_DIM, 512, 0, stream>>>(query, pos, W, bias,
                                               ws_mean, ws_std, out_mean);
    ctx_kernel<<<dim3(S_DIM / CH, B_DIM), 128, 0, stream>>>(emb, mask,
                                                            ws_mean, ws_std, out_ctx);
}

// Round 7
// 130.794 us; speedup vs baseline: 1.3218x; 1.3218x over previous
//
#include <hip/hip_runtime.h>
#include <hip/hip_bf16.h>

// GaussianAttention: S=512, B=32, T=1024, E=512, Q=128. f32 in / f32 out.
// out = [ new_context (S*B*E) | mean (S*B) ].
//
// K0: wave per (s,b): d0=q.w0, d1=q.w1 shuffle-reduced; mraw/std stored [B,S].
// K1: 32 blocks x 64 thr: barrier-free scan (serial-8 + wave shuffle scan).
// K2: block = (16-s chunk, b): union Gaussian window loaded once per row,
//     16 weights from LDS, 16 float4 accumulators. Weights < exp(-20) dropped
//     (tail < 1e-5 vs measured floor 0.03).
//
// NOTE (R6 post-mortem): do NOT fuse K0+K1 into one block-per-b kernel —
// 32 blocks = 2.5% occupancy, 53 us (latency-bound serial dot chain).
// Dispatch-gap saving (~2 us) never pays for lost grid parallelism.

#define S_DIM 512
#define B_DIM 32
#define T_DIM 1024
#define E_DIM 512
#define Q_DIM 128
#define WIN_CUT 20.0f
#define CH 16     // s-values per K2 block
#define TSEG 64   // t-segment (union window is ~14-40 rows, 64 covers it)

// K0: 4 waves/block, one (s,b) pair per wave. grid = S*B/4 = 4096.
__global__ __launch_bounds__(256) void dot_kernel(
    const float* __restrict__ query,  // [S,B,Q]
    const float* __restrict__ W,      // [2,Q]
    const float* __restrict__ bias,   // [2]
    float* __restrict__ ws_mraw,      // [B,S]
    float* __restrict__ ws_std)       // [B,S]
{
    const int wave = threadIdx.x >> 6;
    const int lane = threadIdx.x & 63;
    const int pair = blockIdx.x * 4 + wave;       // = s*B + b
    const float2* qp = (const float2*)(query + (size_t)pair * Q_DIM);
    float2 v = qp[lane];
    float d0 = v.x * W[2 * lane]         + v.y * W[2 * lane + 1];
    float d1 = v.x * W[Q_DIM + 2 * lane] + v.y * W[Q_DIM + 2 * lane + 1];
    #pragma unroll
    for (int off = 32; off; off >>= 1) {
        d0 += __shfl_down(d0, off);
        d1 += __shfl_down(d1, off);
    }
    if (lane == 0) {
        int s = pair / B_DIM, b = pair % B_DIM;
        ws_mraw[(size_t)b * S_DIM + s] = expf(d0 + bias[0]);
        ws_std[(size_t)b * S_DIM + s]  = expf(d1 + bias[1]);
    }
}

// K1: one block (64 thr) per b. lane handles 8 consecutive s. No barriers.
__global__ __launch_bounds__(64) void scan_kernel(
    const float* __restrict__ ws_mraw,   // [B,S]
    const float* __restrict__ position,  // [S,B]
    float* __restrict__ ws_mean,         // [B,S]
    float* __restrict__ out_mean)        // [S,B] f32
{
    const int b = blockIdx.x;
    const int lane = threadIdx.x;
    const float4* src = (const float4*)(ws_mraw + (size_t)b * S_DIM + lane * 8);
    float4 x0 = src[0], x1 = src[1];
    float v[8] = {x0.x, x0.y, x0.z, x0.w, x1.x, x1.y, x1.z, x1.w};
    float pre[8], run = 0.f;
    #pragma unroll
    for (int j = 0; j < 8; ++j) { run += v[j]; pre[j] = run; }
    float tot = run, sc = tot;
    #pragma unroll
    for (int off = 1; off < 64; off <<= 1) {
        float u = __shfl_up(sc, off);
        if (lane >= off) sc += u;
    }
    float excl = sc - tot;
    #pragma unroll
    for (int j = 0; j < 8; ++j) {
        int s = lane * 8 + j;
        float m = position[(size_t)s * B_DIM + b] + (excl + pre[j]) * 0.05f;
        ws_mean[(size_t)b * S_DIM + s] = m;
        out_mean[(size_t)s * B_DIM + b] = m;
    }
}

// K2: grid (S/CH, B), 128 threads. 16 s share each emb-row read.
__global__ __launch_bounds__(128) void ctx_kernel(
    const float* __restrict__ emb,     // [T,B,E]
    const float* __restrict__ mask,    // [T,B]
    const float* __restrict__ ws_mean, // [B,S]
    const float* __restrict__ ws_std,  // [B,S]
    float* __restrict__ out)           // [S,B,E]
{
    __shared__ float lds_w[TSEG * CH];
    __shared__ float lds_mean[CH], lds_std[CH];
    __shared__ int s_tlo, s_thi;
    const int c = blockIdx.x, b = blockIdx.y;
    const int s0 = c * CH;
    const int tid = threadIdx.x;

    if (tid < CH) {
        lds_mean[tid] = ws_mean[(size_t)b * S_DIM + s0 + tid];
        lds_std[tid]  = ws_std[(size_t)b * S_DIM + s0 + tid];
    }
    __syncthreads();
    if (tid == 0) {
        float lo = 1e30f, hi = -1e30f;
        #pragma unroll
        for (int i = 0; i < CH; ++i) {
            float r = __fsqrt_rn(WIN_CUT / lds_std[i]);
            lo = fminf(lo, lds_mean[i] - r);
            hi = fmaxf(hi, lds_mean[i] + r);
        }
        int tlo = (int)floorf(lo);
        if (tlo < 0) tlo = 0; if (tlo > T_DIM - 1) tlo = T_DIM - 1;
        int thi = (int)ceilf(hi);
        if (thi > T_DIM - 1) thi = T_DIM - 1; if (thi < tlo) thi = tlo;
        s_tlo = tlo; s_thi = thi;
    }
    __syncthreads();
    const int tlo = s_tlo, thi = s_thi;

    float4 acc[CH];
    #pragma unroll
    for (int i = 0; i < CH; ++i) acc[i] = float4{0.f, 0.f, 0.f, 0.f};

    for (int tseg = tlo; tseg <= thi; tseg += TSEG) {
        // Precompute weights: thread covers one t (toff = tid>>1), 8 i-slots.
        {
            const int toff = tid >> 1;
            const int ibase = (tid & 1) * 8;
            const int t = tseg + toff;
            float mv = 0.f;
            if (t <= thi) mv = mask[(size_t)t * B_DIM + b];
            #pragma unroll
            for (int j = 0; j < 8; ++j) {
                int i = ibase + j;
                float d = lds_mean[i] - (float)t;
                float w = (t <= thi) ? __expf(-lds_std[i] * d * d) * mv : 0.f;
                lds_w[toff * CH + i] = w;
            }
        }
        __syncthreads();
        const int tend = (thi < tseg + TSEG - 1) ? thi : (tseg + TSEG - 1);
        for (int t = tseg; t <= tend; ++t) {
            const int toff = t - tseg;
            const float4 v =
                ((const float4*)(emb + ((size_t)t * B_DIM + b) * E_DIM))[tid];
            const float* wrow = lds_w + toff * CH;
            #pragma unroll
            for (int i = 0; i < CH; ++i) {
                float w = wrow[i];
                acc[i].x += w * v.x; acc[i].y += w * v.y;
                acc[i].z += w * v.z; acc[i].w += w * v.w;
            }
        }
        __syncthreads();
    }
    #pragma unroll
    for (int i = 0; i < CH; ++i)
        ((float4*)(out + ((size_t)(s0 + i) * B_DIM + b) * E_DIM))[tid] = acc[i];
}

extern "C" void kernel_launch(void* const* d_in, const int* in_sizes, int n_in,
                              void* d_out, int out_size, void* d_ws, size_t ws_size,
                              hipStream_t stream) {
    const float* query = (const float*)d_in[0]; // [S,B,Q]
    const float* emb   = (const float*)d_in[1]; // [T,B,E]
    const float* mask  = (const float*)d_in[2]; // [T,B]
    const float* pos   = (const float*)d_in[3]; // [S,B]
    const float* W     = (const float*)d_in[4]; // [2,Q]
    const float* bias  = (const float*)d_in[5]; // [2]

    float* out_ctx  = (float*)d_out;                            // S*B*E
    float* out_mean = out_ctx + (size_t)S_DIM * B_DIM * E_DIM;  // S*B

    float* ws_mraw = (float*)d_ws;                      // [B,S]
    float* ws_std  = ws_mraw + (size_t)S_DIM * B_DIM;   // [B,S]
    float* ws_mean = ws_std  + (size_t)S_DIM * B_DIM;   // [B,S] (192 KiB total)

    dot_kernel<<<(S_DIM * B_DIM) / 4, 256, 0, stream>>>(query, W, bias, ws_mraw, ws_std);
    scan_kernel<<<B_DIM, 64, 0, stream>>>(ws_mraw, pos, ws_mean, out_mean);
    ctx_kernel<<<dim3(S_DIM / CH, B_DIM), 128, 0, stream>>>(emb, mask, ws_mean, ws_std, out_ctx);
}